// Round 7
// baseline (185.529 us; speedup 1.0000x reference)
//
#include <hip/hip_runtime.h>

#define NB    32
#define CIN   64
#define COUT  128
#define HH    56
#define WW    56
#define HP    58
#define NPIX  (NB*HH*WW)
#define BN_EPSF 1e-5f

#define NXPAD (NB*CIN*HP*HP)     // 6,889,472 padded bf16 elems

typedef __bf16 bf16x8 __attribute__((ext_vector_type(8)));
typedef float  f32x4  __attribute__((ext_vector_type(4)));

// ---- prep: x -> zero-padded NCHW bf16; assemble block-diag w -> bf16; zero sums
__global__ __launch_bounds__(256) void prep(
    const float* __restrict__ x, const float* __restrict__ wb,
    __bf16* __restrict__ xpad, __bf16* __restrict__ whi, float* __restrict__ gsum)
{
    int idx = blockIdx.x * 256 + threadIdx.x;
    if (idx < NXPAD) {
        int wp = idx % HP, r = idx / HP;
        int hp = r % HP, ci = r / HP;            // ci = n*64+ic
        __bf16 v = (__bf16)0.0f;
        if (hp >= 1 && hp <= 56 && wp >= 1 && wp <= 56)
            v = (__bf16)x[(ci * HH + (hp - 1)) * WW + (wp - 1)];
        xpad[idx] = v;
        return;
    }
    idx -= NXPAD;
    if (idx < 576 * 128) {
        int col = idx >> 7, oc = idx & 127;      // col = ic*9 + kh*3 + kw
        int p = oc >> 3, i = oc & 7, q = col >> 3, j = col & 7;
        float v = wb[((p * 72 + q) * 8 + i) * 8 + j];
        int ic = col / 9, tap = col % 9;
        int dst = ((tap * 2 + (ic >> 5)) * 128 + oc) * 32 + (ic & 31);
        whi[dst] = (__bf16)v;
        return;
    }
    idx -= 576 * 128;
    if (idx < 256) gsum[idx] = 0.0f;             // gsum[128] + gsq[128]
}

// ---------------- MFMA conv: weights-in-registers, barrier-free K-loop -------
// block: image n, 8x8 px tile, 64-oc half. 4 waves x 16 oc.
// Wave holds ALL K=576 B-fragments for its 16 oc in 72 VGPRs (loaded once).
// K-loop: 1 ds_read_b128 + 1 MFMA per step, fully unrolled, no barriers.
__global__ __launch_bounds__(256, 4) void conv_mfma(
    const __bf16* __restrict__ xpad, const __bf16* __restrict__ whi,
    float* __restrict__ y, float* __restrict__ gsum, float* __restrict__ gsq)
{
    __shared__ __bf16 xs[100 * 64];      // [halo px 10x10][64 ic], swizzled

    int b = blockIdx.x;
    int ocb = b & 1;                     // oc half: 0 -> 0..63, 1 -> 64..127
    int tile = b >> 1;
    int n = tile / 49, t = tile % 49;
    int h0 = (t / 7) * 8, w0 = (t % 7) * 8;
    int tid  = threadIdx.x;
    int lane = tid & 63, wid = tid >> 6;
    int l15 = lane & 15, l4 = lane >> 4;
    int oc0 = ocb * 64 + wid * 16;

    // ---- load ALL B-fragments for this wave's 16 oc (one-time, L2-resident)
    int woff = (oc0 + l15) * 32 + l4 * 8;
    bf16x8 barr[18];
    #pragma unroll
    for (int th = 0; th < 18; ++th)
        barr[th] = *(const bf16x8*)&whi[th * 4096 + woff];

    // ---- stage x halo: thread = (chunk c of 8 ic, px); swizzled 16B writes
    const __bf16* xn = xpad + n * CIN * HP * HP;
    for (int u = tid; u < 800; u += 256) {
        int c = u / 100, px = u - c * 100;
        int r = px / 10, cc = px - r * 10;
        const __bf16* src = xn + (c * 8) * (HP * HP) + (h0 + r) * HP + (w0 + cc);
        bf16x8 hv;
        #pragma unroll
        for (int j = 0; j < 8; ++j) hv[j] = src[j * HP * HP];
        *(bf16x8*)&xs[px * 64 + ((c ^ (px & 7)) * 8)] = hv;
    }
    __syncthreads();

    f32x4 acc[4] = {};
    int rb0 = (l15 >> 3) * 10 + (l15 & 7);       // halo row*10+col base

    #pragma unroll
    for (int th = 0; th < 18; ++th) {
        const int tap = th >> 1, half = th & 1;
        const int kh = tap / 3, kw = tap - kh * 3;
        const int toff = kh * 10 + kw;
        int c0 = half * 4 + l4;
        #pragma unroll
        for (int mt = 0; mt < 4; ++mt) {
            int R  = rb0 + mt * 20 + toff;
            int ae = R * 64 + ((c0 ^ (R & 7)) * 8);
            bf16x8 ah = *(const bf16x8*)&xs[ae];
            acc[mt] = __builtin_amdgcn_mfma_f32_16x16x32_bf16(ah, barr[th], acc[mt], 0, 0, 0);
        }
    }

    // ---- write raw y (pre-BN): float4 per mt ----
    // C/D layout: col(oc_local)=lane&15, row(M-local)=(lane>>4)*4 + reg  [m89]
    float* yn = y + n * COUT * HH * WW;
    int pyb = l4 >> 1;
    int gwo = w0 + (l4 & 1) * 4;
    int oc  = oc0 + l15;
    #pragma unroll
    for (int mt = 0; mt < 4; ++mt) {
        int gh = h0 + mt * 2 + pyb;
        *(float4*)&yn[(oc * HH + gh) * WW + gwo] = *(float4*)&acc[mt];
    }

    // ---- per-channel partial stats; red aliases xs (all xs reads done) ----
    float* red = (float*)xs;
    __syncthreads();
    {
        float s = 0.0f, sq = 0.0f;
        #pragma unroll
        for (int mt = 0; mt < 4; ++mt)
            #pragma unroll
            for (int r = 0; r < 4; ++r) {
                float v = acc[mt][r];
                s += v; sq += v * v;
            }
        s  += __shfl_xor(s, 16, 64);  s  += __shfl_xor(s, 32, 64);
        sq += __shfl_xor(sq, 16, 64); sq += __shfl_xor(sq, 32, 64);
        if (l4 == 0) {
            int o = wid * 16 + l15;              // 0..63 within block
            red[o] = s; red[64 + o] = sq;
        }
    }
    __syncthreads();
    if (tid < 64) {
        atomicAdd(&gsum[ocb * 64 + tid], red[tid]);
        atomicAdd(&gsq [ocb * 64 + tid], red[64 + tid]);
    }
}

// ---------------- BN scale/shift from accumulated stats ----------------------
__global__ void bn_finalize(const float* __restrict__ gsum, const float* __restrict__ gsq,
                            const float* __restrict__ gamma, const float* __restrict__ beta,
                            float* __restrict__ scale, float* __restrict__ shift)
{
    int c = threadIdx.x;
    float mean = gsum[c] * (1.0f / NPIX);
    float var  = gsq[c]  * (1.0f / NPIX) - mean * mean;
    float inv  = gamma[c] / sqrtf(var + BN_EPSF);
    scale[c] = inv;
    shift[c] = beta[c] - mean * inv;
}

// ---------------- apply BN + clip, in-place on d_out, float4 -----------------
__global__ __launch_bounds__(256) void bn_apply(float* __restrict__ y,
        const float* __restrict__ scale, const float* __restrict__ shift)
{
    const int total4 = NB * COUT * HH * WW / 4;   // 3211264
    int idx = blockIdx.x * blockDim.x + threadIdx.x;
    int stride = gridDim.x * blockDim.x;
    for (int i4 = idx; i4 < total4; i4 += stride) {
        int c = (i4 / 784) & 127;
        float sc = scale[c], sh = shift[c];
        float4 v = ((float4*)y)[i4];
        v.x = fminf(fmaxf(fmaf(v.x, sc, sh), 0.0f), 6.0f);
        v.y = fminf(fmaxf(fmaf(v.y, sc, sh), 0.0f), 6.0f);
        v.z = fminf(fmaxf(fmaf(v.z, sc, sh), 0.0f), 6.0f);
        v.w = fminf(fmaxf(fmaf(v.w, sc, sh), 0.0f), 6.0f);
        ((float4*)y)[i4] = v;
    }
}

extern "C" void kernel_launch(void* const* d_in, const int* in_sizes, int n_in,
                              void* d_out, int out_size, void* d_ws, size_t ws_size,
                              hipStream_t stream) {
    const float* x     = (const float*)d_in[0];
    const float* wb    = (const float*)d_in[1];
    const float* gamma = (const float*)d_in[2];
    const float* beta  = (const float*)d_in[3];
    float* y = (float*)d_out;

    __bf16* xpad = (__bf16*)d_ws;                // 6,889,472 bf16 = 13.78 MB
    __bf16* whi  = xpad + NXPAD;                 // 73728 bf16
    float* gsum  = (float*)(whi + 73728);
    float* gsq   = gsum + 128;
    float* scale = gsq + 128;
    float* shift = scale + 128;

    int prep_grid = (NXPAD + 576 * 128 + 256 + 255) / 256;   // 27201
    prep<<<prep_grid, 256, 0, stream>>>(x, wb, xpad, whi, gsum);
    conv_mfma<<<NB * 49 * 2, 256, 0, stream>>>(xpad, whi, y, gsum, gsq);
    bn_finalize<<<1, COUT, 0, stream>>>(gsum, gsq, gamma, beta, scale, shift);
    bn_apply<<<2048, 256, 0, stream>>>(y, scale, shift);
}